// Round 17
// baseline (242.373 us; speedup 1.0000x reference)
//
#include <hip/hip_runtime.h>
#include <hip/hip_bf16.h>

typedef short bf16x8 __attribute__((ext_vector_type(8)));
typedef float f32x4 __attribute__((ext_vector_type(4)));
typedef float f32x16 __attribute__((ext_vector_type(16)));
typedef unsigned short u16;
typedef unsigned int u32;

__device__ __forceinline__ u16 f2b(float f) {
  __hip_bfloat16 h = __float2bfloat16(f);
  return *reinterpret_cast<u16*>(&h);
}

#define MFMA16(a, b, c) __builtin_amdgcn_mfma_f32_16x16x32_bf16((a), (b), (c), 0, 0, 0)
#define MFMA32(a, b, c) __builtin_amdgcn_mfma_f32_32x32x16_bf16((a), (b), (c), 0, 0, 0)

// B=2 S=2048 D=1024 H=16 DC=64 HC=16 HD=64

// ---------- fused homogeneous prep: cvt (4096 blocks) | wT Wv (256) | wT Wo (256) ----------
__global__ __launch_bounds__(256) void k_prep2(const float* __restrict__ hs,
                                               u16* __restrict__ HSb,
                                               const float* __restrict__ Wv,
                                               u16* __restrict__ WvT,
                                               const float* __restrict__ Wo,
                                               u16* __restrict__ WoT) {
  __shared__ float t[64][65];
  int tid = threadIdx.x, blk = blockIdx.x;
  if (blk < 4096) {
    int i = (blk * 256 + tid) * 4;
    float4 v = *reinterpret_cast<const float4*>(hs + i);
    ushort4 o;
    o.x = f2b(v.x); o.y = f2b(v.y); o.z = f2b(v.z); o.w = f2b(v.w);
    *reinterpret_cast<ushort4*>(HSb + i) = o;
    return;
  }
  const float* W = (blk < 4352) ? Wv : Wo;
  u16* WT = (blk < 4352) ? WvT : WoT;
  int bid = (blk < 4352) ? blk - 4096 : blk - 4352;
  int r0 = (bid & 15) << 6, c0 = (bid >> 4) << 6;
#pragma unroll
  for (int rep = 0; rep < 4; ++rep) {
    int e = tid + rep * 256;
    int r = e >> 4, c4 = (e & 15) << 2;
    float4 v = *reinterpret_cast<const float4*>(W + (size_t)(r0 + r) * 1024 + c0 + c4);
    t[r][c4] = v.x; t[r][c4 + 1] = v.y; t[r][c4 + 2] = v.z; t[r][c4 + 3] = v.w;
  }
  __syncthreads();
#pragma unroll
  for (int rep = 0; rep < 4; ++rep) {
    int e = tid + rep * 256;
    int c = e >> 4, r4 = (e & 15) << 2;
    ushort4 o;
    o.x = f2b(t[r4][c]); o.y = f2b(t[r4 + 1][c]);
    o.z = f2b(t[r4 + 2][c]); o.w = f2b(t[r4 + 3][c]);
    *reinterpret_cast<ushort4*>(WT + (size_t)(c0 + c) * 1024 + r0 + r4) = o;
  }
}

// ---------- z = coords@Wc+bc; emit Z, Zg(=2g2*z), zghl(hi/lo of -g2*|z|^2) ----------
__global__ void k_z(const float* __restrict__ C, const float* __restrict__ Wc,
                    const float* __restrict__ bc, const float* __restrict__ gamma,
                    u16* __restrict__ Z, u16* __restrict__ Zg, u32* __restrict__ zghl) {
  int gid = blockIdx.x * 256 + threadIdx.x;  // 65536 = (B*S)*H
  int bs = gid >> 4, h = gid & 15;
  float gm = gamma[h];
  float g = (gm > 15.f) ? gm : log1pf(__expf(gm));
  float g2 = g * 1.4426950408889634f;
  float tg2 = 2.f * g2;
  const float* crow = C + (size_t)bs * 64;
  float acc[16];
#pragma unroll
  for (int c = 0; c < 16; ++c) acc[c] = bc[h * 16 + c];
  for (int k = 0; k < 64; ++k) {
    float cv = crow[k];
    const float* wr = Wc + (size_t)k * 256 + h * 16;
#pragma unroll
    for (int c = 0; c < 16; ++c) acc[c] = fmaf(cv, wr[c], acc[c]);
  }
  float sq = 0.f;
  u16 tz[16], tg[16];
#pragma unroll
  for (int c = 0; c < 16; ++c) {
    sq += acc[c] * acc[c];
    tz[c] = f2b(acc[c]);
    tg[c] = f2b(tg2 * acc[c]);
  }
  float x = -g2 * sq;
  u32 xu = __float_as_uint(x);
  float xh = __uint_as_float(xu & 0xFFFF0000u);
  u32 packed = (xu >> 16) | ((u32)f2b(x - xh) << 16);
  int b = bs >> 11, s = bs & 2047;
  int bh = (b << 4) + h;
  size_t ro = (((size_t)bh << 11) + s) * 16;
  *reinterpret_cast<uint4*>(Z + ro) = *reinterpret_cast<uint4*>(tz);
  *reinterpret_cast<uint4*>(Z + ro + 8) = *reinterpret_cast<uint4*>(tz + 8);
  *reinterpret_cast<uint4*>(Zg + ro) = *reinterpret_cast<uint4*>(tg);
  *reinterpret_cast<uint4*>(Zg + ro + 8) = *reinterpret_cast<uint4*>(tg + 8);
  zghl[((size_t)bh << 11) + s] = packed;
}

// ---------- updated_coords = coords @ Wn + bn (fp32) ----------
__global__ void k_coords(const float* __restrict__ C, const float* __restrict__ Wn,
                         const float* __restrict__ bn, float* __restrict__ out) {
  int gid = blockIdx.x * 256 + threadIdx.x;  // 262144
  int bs = gid >> 6, c = gid & 63;
  const float* crow = C + (size_t)bs * 64;
  float acc = bn[c];
#pragma unroll 8
  for (int k = 0; k < 64; ++k) acc = fmaf(crow[k], Wn[k * 64 + c], acc);
  out[gid] = acc;
}

// ---------- GEMM: 128x64 tile, 2-phase pipelined, bm-major XCD partition ----------
template <int OUTM>
__global__ __launch_bounds__(512, 4) void k_gemm(const u16* __restrict__ A,
                                                 const u16* __restrict__ BT,
                                                 const float* __restrict__ bias,
                                                 void* __restrict__ Cout,
                                                 int M, int N, int K) {
  __shared__ u16 As[2][128 * 64];
  __shared__ u16 Bs[2][64 * 64];
  int wg = ((blockIdx.x & 7) << 6) + (blockIdx.x >> 3);
  int bm = wg >> 4, bn = wg & 15;
  int tid = threadIdx.x, lane = tid & 63, w = tid >> 6;
  int wm = w >> 1, wn = w & 1;
  int l15 = lane & 15, lg = lane >> 4;
  int lr = lane >> 3;
  int swc = (lane & 7) ^ lr;

  f32x4 acc[2][2];
#pragma unroll
  for (int mi = 0; mi < 2; ++mi)
#pragma unroll
    for (int ni = 0; ni < 2; ++ni) acc[mi][ni] = (f32x4){0.f, 0.f, 0.f, 0.f};

  const u16* Abase = A + (size_t)(bm * 128 + w * 8 + lr) * K + swc * 8;
  const u16* Bbase = BT + (size_t)(bn * 64 + w * 8 + lr) * K + swc * 8;
  int rsw = l15 & 7;

#define GSTAGE(BUF, KK)                                                             \
  do {                                                                              \
    __builtin_amdgcn_global_load_lds(                                               \
        (const __attribute__((address_space(1))) u32*)(Abase + (KK)),               \
        (__attribute__((address_space(3))) u32*)&As[(BUF)][(w * 8) * 64], 16, 0, 0);\
    __builtin_amdgcn_global_load_lds(                                               \
        (const __attribute__((address_space(1))) u32*)(Abase + (size_t)64 * K + (KK)),\
        (__attribute__((address_space(3))) u32*)&As[(BUF)][(64 + w * 8) * 64], 16, 0, 0);\
    __builtin_amdgcn_global_load_lds(                                               \
        (const __attribute__((address_space(1))) u32*)(Bbase + (KK)),               \
        (__attribute__((address_space(3))) u32*)&Bs[(BUF)][(w * 8) * 64], 16, 0, 0);\
  } while (0)

  const int nk = K >> 6;
  GSTAGE(0, 0);
  for (int it = 0; it < nk; ++it) {
    int cur = it & 1;
    if (it + 1 < nk) {
      GSTAGE(cur ^ 1, (it + 1) * 64);
      asm volatile("s_waitcnt vmcnt(3)" ::: "memory");
    } else {
      asm volatile("s_waitcnt vmcnt(0)" ::: "memory");
    }
    __builtin_amdgcn_sched_barrier(0);
    __builtin_amdgcn_s_barrier();
#pragma unroll
    for (int kk = 0; kk < 2; ++kk) {
      int ch = (kk * 4 + lg) ^ rsw;
      bf16x8 af[2], bfr[2];
#pragma unroll
      for (int mi = 0; mi < 2; ++mi)
        af[mi] = *reinterpret_cast<const bf16x8*>(&As[cur][(wm * 32 + mi * 16 + l15) * 64 + ch * 8]);
#pragma unroll
      for (int ni = 0; ni < 2; ++ni)
        bfr[ni] = *reinterpret_cast<const bf16x8*>(&Bs[cur][(wn * 32 + ni * 16 + l15) * 64 + ch * 8]);
#pragma unroll
      for (int mi = 0; mi < 2; ++mi)
#pragma unroll
        for (int ni = 0; ni < 2; ++ni)
          acc[mi][ni] = MFMA16(af[mi], bfr[ni], acc[mi][ni]);
    }
    __builtin_amdgcn_sched_barrier(0);
    __builtin_amdgcn_s_barrier();
  }
#undef GSTAGE

#pragma unroll
  for (int mi = 0; mi < 2; ++mi) {
#pragma unroll
    for (int ni = 0; ni < 2; ++ni) {
      int col = bn * 64 + wn * 32 + ni * 16 + l15;
      float bv = bias[col];
      if (OUTM == 0) {
#pragma unroll
        for (int j = 0; j < 4; ++j) {
          int row = bm * 128 + wm * 32 + mi * 16 + lg * 4 + j;
          reinterpret_cast<float*>(Cout)[(size_t)row * N + col] = acc[mi][ni][j] + bv;
        }
      } else {
        // VF[bh][tg][dh][hi*32+lv][j] = V[tg*16 + hi*8 + j][dh*32 + lv]
        int row0 = bm * 128 + wm * 32 + mi * 16 + lg * 4;
        int b = row0 >> 11, tg = (row0 >> 4) & 127;
        int hi_ = lg >> 1, jb = (lg & 1) << 2;
        int h = col >> 6, hd = col & 63, dh = hd >> 5, lv = hd & 31;
        size_t addr = ((((size_t)(b * 16 + h) * 128 + tg) * 2 + dh) << 9) +
                      ((hi_ * 32 + lv) << 3) + jb;
        ushort4 o;
        o.x = f2b(acc[mi][ni][0] + bv); o.y = f2b(acc[mi][ni][1] + bv);
        o.z = f2b(acc[mi][ni][2] + bv); o.w = f2b(acc[mi][ni][3] + bv);
        *reinterpret_cast<ushort4*>(reinterpret_cast<u16*>(Cout) + addr) = o;
      }
    }
  }
}

// ---------- flash attention: q=64/block (grid 1024, 4 blocks/CU), lean body ----------
// Each wave: one 32-q block x one t-half. Gamma-folded aug-MFMA scores,
// qpart precomputed, vb in registers, per-wave LDS P scratch (ping-pong),
// no barriers in loop, XCD-swizzled grid.
__global__ __launch_bounds__(256, 4) void k_attn(const u16* __restrict__ Z,
                                                 const u16* __restrict__ Zg,
                                                 const u32* __restrict__ zghl,
                                                 const u16* __restrict__ VF,
                                                 u16* __restrict__ O) {
  // smem: [0,16384) P ping-pong (2 x 4 waves x 2KB); end-phase oacc spill
  // reuses [0,16384). [16384,16896) psq[4][32].
  __shared__ __align__(16) char smem[16896];
  float* psqf = reinterpret_cast<float*>(smem + 16384);

  int tid = threadIdx.x, lane = tid & 63, w = tid >> 6;
  int l31 = lane & 31, hi = lane >> 5;
  int hi4 = hi << 2, hi8 = hi << 3;
  int th = w & 1, qh = w >> 1, th32 = th << 5;
  // XCD swizzle (1024 = 8 x 128, bijective)
  int wg = ((blockIdx.x & 7) << 7) + (blockIdx.x >> 3);
  int bh = wg >> 5, qt = wg & 31;
  int q0 = qt << 6;  // 64 q per block
  int h = bh & 15, bb = bh >> 4;

  const u16* Zb = Z + ((size_t)bh << 11) * 16;
  const u16* Zgb = Zg + ((size_t)bh << 11) * 16;
  const u32* ghl = zghl + ((size_t)bh << 11);
  const u16* VFb = VF + ((size_t)bh << 17);

  int qx = (qh << 5) + l31;  // lane q (local to 64)

  bf16x8 zq2 = *reinterpret_cast<const bf16x8*>(Zgb + (size_t)(q0 + qx) * 16 + hi8);

  u32 gq = ghl[q0 + qx];
  uint4 ab0 = {0x3F803F80u, gq, 0u, 0u};
  if (hi) { ab0.x = 0u; ab0.y = 0u; }
  bf16x8 aug_b = *reinterpret_cast<bf16x8*>(&ab0);

  uint4 aqu = {0u, 0x3F803F80u, 0u, 0u};
  if (hi) aqu.y = 0u;
  bf16x8 aug_q = *reinterpret_cast<bf16x8*>(&aqu);
  f32x16 qpart = MFMA32(aug_q, aug_b, (f32x16){});

  const u16* zap = Zb + (size_t)(th32 + l31) * 16 + hi8;
  const u32* xtp = ghl + th32 + l31;
  const u16* vwp = VFb + ((size_t)th << 11) + ((size_t)lane << 3);

  f32x16 oacc0 = {}, oacc1 = {};
  f32x4 ps = {};

  int swz = (l31 ^ (l31 >> 2)) & 3;
  char* pbase = smem + (w << 11) + l31 * 64;

  bf16x8 zA_c = *reinterpret_cast<const bf16x8*>(zap);
  u32 zhl_c = xtp[0];
  bf16x8 vc0 = *reinterpret_cast<const bf16x8*>(vwp);
  bf16x8 vc1 = *reinterpret_cast<const bf16x8*>(vwp + 512);
  bf16x8 vc2 = *reinterpret_cast<const bf16x8*>(vwp + 1024);
  bf16x8 vc3 = *reinterpret_cast<const bf16x8*>(vwp + 1536);

#pragma unroll 2
  for (int tt = 0; tt < 32; ++tt) {
    const int t0 = tt << 6;
    bf16x8 zA_n = zA_c, vn0 = vc0, vn1 = vc1, vn2 = vc2, vn3 = vc3;
    u32 zhl_n = zhl_c;
    if (tt < 31) {
      const u16* vtb = vwp + ((tt + 1) << 12);
      zA_n = *reinterpret_cast<const bf16x8*>(zap + (size_t)(t0 + 64) * 16);
      zhl_n = xtp[t0 + 64];
      vn0 = *reinterpret_cast<const bf16x8*>(vtb);
      vn1 = *reinterpret_cast<const bf16x8*>(vtb + 512);
      vn2 = *reinterpret_cast<const bf16x8*>(vtb + 1024);
      vn3 = *reinterpret_cast<const bf16x8*>(vtb + 1536);
    }

    uint4 aau = {hi ? 0u : zhl_c, 0u, 0u, 0u};
    bf16x8 aug_a = *reinterpret_cast<bf16x8*>(&aau);

    f32x16 sc = MFMA32(aug_a, aug_b, qpart);
    sc = MFMA32(zA_c, zq2, sc);

    char* pb = pbase + ((tt & 1) << 13);
#pragma unroll
    for (int g = 0; g < 4; ++g) {
      int cb = ((g ^ swz) << 4) + (hi << 3);
      float e0 = fminf(sc[g * 4 + 0], 0.f), e1 = fminf(sc[g * 4 + 1], 0.f);
      float e2 = fminf(sc[g * 4 + 2], 0.f), e3 = fminf(sc[g * 4 + 3], 0.f);
      float p0 = __builtin_amdgcn_exp2f(e0), p1 = __builtin_amdgcn_exp2f(e1);
      float p2 = __builtin_amdgcn_exp2f(e2), p3 = __builtin_amdgcn_exp2f(e3);
      ps[0] += p0; ps[1] += p1; ps[2] += p2; ps[3] += p3;
      u32 pk0, pk1;
      asm("v_cvt_pk_bf16_f32 %0, %1, %2" : "=v"(pk0) : "v"(p0), "v"(p1));
      asm("v_cvt_pk_bf16_f32 %0, %1, %2" : "=v"(pk1) : "v"(p2), "v"(p3));
      uint2 pkv = {pk0, pk1};
      *reinterpret_cast<uint2*>(pb + cb) = pkv;
    }

    int c0b = (((0 * 2 + hi) ^ swz) << 4);
    int c1b = (((1 * 2 + hi) ^ swz) << 4);
    bf16x8 pa0 = *reinterpret_cast<const bf16x8*>(pb + c0b);
    bf16x8 pa1 = *reinterpret_cast<const bf16x8*>(pb + c1b);

    __builtin_amdgcn_s_setprio(1);
    oacc0 = MFMA32(pa0, vc0, oacc0);
    oacc1 = MFMA32(pa0, vc1, oacc1);
    oacc0 = MFMA32(pa1, vc2, oacc0);
    oacc1 = MFMA32(pa1, vc3, oacc1);
    __builtin_amdgcn_s_setprio(0);

    zA_c = zA_n; zhl_c = zhl_n;
    vc0 = vn0; vc1 = vn1; vc2 = vn2; vc3 = vn3;
  }

  float psum = (ps[0] + ps[1]) + (ps[2] + ps[3]);
  psum += __shfl_xor(psum, 32, 64);

  __syncthreads();
  if (th == 1) {  // spill t-half 1 partials
    char* dst = smem + ((w >> 1) << 13) + lane * 16;
#pragma unroll
    for (int r = 0; r < 4; ++r) {
      *reinterpret_cast<f32x4*>(dst + (0 + r) * 1024) =
          (f32x4){oacc0[r * 4], oacc0[r * 4 + 1], oacc0[r * 4 + 2], oacc0[r * 4 + 3]};
      *reinterpret_cast<f32x4*>(dst + (4 + r) * 1024) =
          (f32x4){oacc1[r * 4], oacc1[r * 4 + 1], oacc1[r * 4 + 2], oacc1[r * 4 + 3]};
    }
  }
  if (lane < 32) psqf[w * 32 + l31] = psum;
  __syncthreads();
  if (th == 0) {
    const char* src = smem + ((w >> 1) << 13) + lane * 16;
#pragma unroll
    for (int r = 0; r < 4; ++r) {
      f32x4 v0 = *reinterpret_cast<const f32x4*>(src + (0 + r) * 1024);
      f32x4 v1 = *reinterpret_cast<const f32x4*>(src + (4 + r) * 1024);
#pragma unroll
      for (int j = 0; j < 4; ++j) {
        oacc0[r * 4 + j] += v0[j];
        oacc1[r * 4 + j] += v1[j];
      }
    }
#pragma unroll
    for (int g = 0; g < 4; ++g) {
      f32x4 a = *reinterpret_cast<const f32x4*>(&psqf[w * 32 + (g << 3) + hi4]);
      f32x4 b2 = *reinterpret_cast<const f32x4*>(&psqf[(w + 1) * 32 + (g << 3) + hi4]);
#pragma unroll
      for (int j = 0; j < 4; ++j) {
        float inv = __builtin_amdgcn_rcpf(a[j] + b2[j]);
        int qrow = (g << 3) + hi4 + j;
        int srow = q0 + (qh << 5) + qrow;
        u16* orow = O + ((size_t)(bb * 2048 + srow) << 10) + h * 64 + l31;
        orow[0] = f2b(oacc0[g * 4 + j] * inv);
        orow[32] = f2b(oacc1[g * 4 + j] * inv);
      }
    }
  }
}

extern "C" void kernel_launch(void* const* d_in, const int* in_sizes, int n_in,
                              void* d_out, int out_size, void* d_ws, size_t ws_size,
                              hipStream_t stream) {
  const float* hs     = (const float*)d_in[0];
  const float* coords = (const float*)d_in[1];
  const float* Wv     = (const float*)d_in[2];
  const float* bv     = (const float*)d_in[3];
  const float* Wc     = (const float*)d_in[4];
  const float* bc     = (const float*)d_in[5];
  const float* Wn     = (const float*)d_in[6];
  const float* bn     = (const float*)d_in[7];
  const float* Wo     = (const float*)d_in[8];
  const float* bo     = (const float*)d_in[9];
  const float* gamma  = (const float*)d_in[10];
  float* out_h = (float*)d_out;
  float* out_c = out_h + 4194304;

  char* ws = (char*)d_ws;
  u16*   HSb  = (u16*)(ws + 0);          // 8 MB (reused as O after gemm1)
  u16*   O    = (u16*)(ws + 0);
  u16*   WvT  = (u16*)(ws + 8388608);    // 2 MB
  u16*   WoT  = (u16*)(ws + 10485760);   // 2 MB
  u16*   Zw   = (u16*)(ws + 12582912);   // 2 MB
  u16*   Zgw  = (u16*)(ws + 14680064);   // 2 MB
  u32*   zghl = (u32*)(ws + 16777216);   // 256 KB
  u16*   VFw  = (u16*)(ws + 17039360);   // 8 MB -> total ~25 MB

  k_prep2<<<4608, 256, 0, stream>>>(hs, HSb, Wv, WvT, Wo, WoT);
  k_z<<<256, 256, 0, stream>>>(coords, Wc, bc, gamma, Zw, Zgw, zghl);
  k_gemm<1><<<512, 512, 0, stream>>>(HSb, WvT, bv, VFw, 4096, 1024, 1024);
  k_attn<<<1024, 256, 0, stream>>>(Zw, Zgw, zghl, VFw, O);
  k_gemm<0><<<512, 512, 0, stream>>>(O, WoT, bo, out_h, 4096, 1024, 1024);
  k_coords<<<1024, 256, 0, stream>>>(coords, Wn, bn, out_c);
}

// Round 18
// 107.048 us; speedup vs baseline: 2.2641x; 2.2641x over previous
//
#include <hip/hip_runtime.h>
#include <hip/hip_bf16.h>

typedef short bf16x8 __attribute__((ext_vector_type(8)));
typedef float f32x4 __attribute__((ext_vector_type(4)));
typedef float f32x16 __attribute__((ext_vector_type(16)));
typedef unsigned short u16;
typedef unsigned int u32;

__device__ __forceinline__ u16 f2b(float f) {
  __hip_bfloat16 h = __float2bfloat16(f);
  return *reinterpret_cast<u16*>(&h);
}

#define MFMA16(a, b, c) __builtin_amdgcn_mfma_f32_16x16x32_bf16((a), (b), (c), 0, 0, 0)
#define MFMA32(a, b, c) __builtin_amdgcn_mfma_f32_32x32x16_bf16((a), (b), (c), 0, 0, 0)

// B=2 S=2048 D=1024 H=16 DC=64 HC=16 HD=64

// ---------- fused homogeneous prep: cvt (4096 blocks) | wT Wv (256) | wT Wo (256) ----------
__global__ __launch_bounds__(256) void k_prep2(const float* __restrict__ hs,
                                               u16* __restrict__ HSb,
                                               const float* __restrict__ Wv,
                                               u16* __restrict__ WvT,
                                               const float* __restrict__ Wo,
                                               u16* __restrict__ WoT) {
  __shared__ float t[64][65];
  int tid = threadIdx.x, blk = blockIdx.x;
  if (blk < 4096) {
    int i = (blk * 256 + tid) * 4;
    float4 v = *reinterpret_cast<const float4*>(hs + i);
    ushort4 o;
    o.x = f2b(v.x); o.y = f2b(v.y); o.z = f2b(v.z); o.w = f2b(v.w);
    *reinterpret_cast<ushort4*>(HSb + i) = o;
    return;
  }
  const float* W = (blk < 4352) ? Wv : Wo;
  u16* WT = (blk < 4352) ? WvT : WoT;
  int bid = (blk < 4352) ? blk - 4096 : blk - 4352;
  int r0 = (bid & 15) << 6, c0 = (bid >> 4) << 6;
#pragma unroll
  for (int rep = 0; rep < 4; ++rep) {
    int e = tid + rep * 256;
    int r = e >> 4, c4 = (e & 15) << 2;
    float4 v = *reinterpret_cast<const float4*>(W + (size_t)(r0 + r) * 1024 + c0 + c4);
    t[r][c4] = v.x; t[r][c4 + 1] = v.y; t[r][c4 + 2] = v.z; t[r][c4 + 3] = v.w;
  }
  __syncthreads();
#pragma unroll
  for (int rep = 0; rep < 4; ++rep) {
    int e = tid + rep * 256;
    int c = e >> 4, r4 = (e & 15) << 2;
    ushort4 o;
    o.x = f2b(t[r4][c]); o.y = f2b(t[r4 + 1][c]);
    o.z = f2b(t[r4 + 2][c]); o.w = f2b(t[r4 + 3][c]);
    *reinterpret_cast<ushort4*>(WT + (size_t)(c0 + c) * 1024 + r0 + r4) = o;
  }
}

// ---------- z = coords@Wc+bc; emit Z, Zg(=2g2*z), zghl(hi/lo of -g2*|z|^2) ----------
__global__ void k_z(const float* __restrict__ C, const float* __restrict__ Wc,
                    const float* __restrict__ bc, const float* __restrict__ gamma,
                    u16* __restrict__ Z, u16* __restrict__ Zg, u32* __restrict__ zghl) {
  int gid = blockIdx.x * 256 + threadIdx.x;  // 65536 = (B*S)*H
  int bs = gid >> 4, h = gid & 15;
  float gm = gamma[h];
  float g = (gm > 15.f) ? gm : log1pf(__expf(gm));
  float g2 = g * 1.4426950408889634f;
  float tg2 = 2.f * g2;
  const float* crow = C + (size_t)bs * 64;
  float acc[16];
#pragma unroll
  for (int c = 0; c < 16; ++c) acc[c] = bc[h * 16 + c];
  for (int k = 0; k < 64; ++k) {
    float cv = crow[k];
    const float* wr = Wc + (size_t)k * 256 + h * 16;
#pragma unroll
    for (int c = 0; c < 16; ++c) acc[c] = fmaf(cv, wr[c], acc[c]);
  }
  float sq = 0.f;
  u16 tz[16], tg[16];
#pragma unroll
  for (int c = 0; c < 16; ++c) {
    sq += acc[c] * acc[c];
    tz[c] = f2b(acc[c]);
    tg[c] = f2b(tg2 * acc[c]);
  }
  float x = -g2 * sq;
  u32 xu = __float_as_uint(x);
  float xh = __uint_as_float(xu & 0xFFFF0000u);
  u32 packed = (xu >> 16) | ((u32)f2b(x - xh) << 16);
  int b = bs >> 11, s = bs & 2047;
  int bh = (b << 4) + h;
  size_t ro = (((size_t)bh << 11) + s) * 16;
  *reinterpret_cast<uint4*>(Z + ro) = *reinterpret_cast<uint4*>(tz);
  *reinterpret_cast<uint4*>(Z + ro + 8) = *reinterpret_cast<uint4*>(tz + 8);
  *reinterpret_cast<uint4*>(Zg + ro) = *reinterpret_cast<uint4*>(tg);
  *reinterpret_cast<uint4*>(Zg + ro + 8) = *reinterpret_cast<uint4*>(tg + 8);
  zghl[((size_t)bh << 11) + s] = packed;
}

// ---------- updated_coords = coords @ Wn + bn (fp32) ----------
__global__ void k_coords(const float* __restrict__ C, const float* __restrict__ Wn,
                         const float* __restrict__ bn, float* __restrict__ out) {
  int gid = blockIdx.x * 256 + threadIdx.x;  // 262144
  int bs = gid >> 6, c = gid & 63;
  const float* crow = C + (size_t)bs * 64;
  float acc = bn[c];
#pragma unroll 8
  for (int k = 0; k < 64; ++k) acc = fmaf(crow[k], Wn[k * 64 + c], acc);
  out[gid] = acc;
}

// ---------- GEMM: 128x64 tile, 2-phase pipelined, bm-major XCD partition ----------
template <int OUTM>
__global__ __launch_bounds__(512, 4) void k_gemm(const u16* __restrict__ A,
                                                 const u16* __restrict__ BT,
                                                 const float* __restrict__ bias,
                                                 void* __restrict__ Cout,
                                                 int M, int N, int K) {
  __shared__ u16 As[2][128 * 64];
  __shared__ u16 Bs[2][64 * 64];
  int wg = ((blockIdx.x & 7) << 6) + (blockIdx.x >> 3);
  int bm = wg >> 4, bn = wg & 15;
  int tid = threadIdx.x, lane = tid & 63, w = tid >> 6;
  int wm = w >> 1, wn = w & 1;
  int l15 = lane & 15, lg = lane >> 4;
  int lr = lane >> 3;
  int swc = (lane & 7) ^ lr;

  f32x4 acc[2][2];
#pragma unroll
  for (int mi = 0; mi < 2; ++mi)
#pragma unroll
    for (int ni = 0; ni < 2; ++ni) acc[mi][ni] = (f32x4){0.f, 0.f, 0.f, 0.f};

  const u16* Abase = A + (size_t)(bm * 128 + w * 8 + lr) * K + swc * 8;
  const u16* Bbase = BT + (size_t)(bn * 64 + w * 8 + lr) * K + swc * 8;
  int rsw = l15 & 7;

#define GSTAGE(BUF, KK)                                                             \
  do {                                                                              \
    __builtin_amdgcn_global_load_lds(                                               \
        (const __attribute__((address_space(1))) u32*)(Abase + (KK)),               \
        (__attribute__((address_space(3))) u32*)&As[(BUF)][(w * 8) * 64], 16, 0, 0);\
    __builtin_amdgcn_global_load_lds(                                               \
        (const __attribute__((address_space(1))) u32*)(Abase + (size_t)64 * K + (KK)),\
        (__attribute__((address_space(3))) u32*)&As[(BUF)][(64 + w * 8) * 64], 16, 0, 0);\
    __builtin_amdgcn_global_load_lds(                                               \
        (const __attribute__((address_space(1))) u32*)(Bbase + (KK)),               \
        (__attribute__((address_space(3))) u32*)&Bs[(BUF)][(w * 8) * 64], 16, 0, 0);\
  } while (0)

  const int nk = K >> 6;
  GSTAGE(0, 0);
  for (int it = 0; it < nk; ++it) {
    int cur = it & 1;
    if (it + 1 < nk) {
      GSTAGE(cur ^ 1, (it + 1) * 64);
      asm volatile("s_waitcnt vmcnt(3)" ::: "memory");
    } else {
      asm volatile("s_waitcnt vmcnt(0)" ::: "memory");
    }
    __builtin_amdgcn_sched_barrier(0);
    __builtin_amdgcn_s_barrier();
#pragma unroll
    for (int kk = 0; kk < 2; ++kk) {
      int ch = (kk * 4 + lg) ^ rsw;
      bf16x8 af[2], bfr[2];
#pragma unroll
      for (int mi = 0; mi < 2; ++mi)
        af[mi] = *reinterpret_cast<const bf16x8*>(&As[cur][(wm * 32 + mi * 16 + l15) * 64 + ch * 8]);
#pragma unroll
      for (int ni = 0; ni < 2; ++ni)
        bfr[ni] = *reinterpret_cast<const bf16x8*>(&Bs[cur][(wn * 32 + ni * 16 + l15) * 64 + ch * 8]);
#pragma unroll
      for (int mi = 0; mi < 2; ++mi)
#pragma unroll
        for (int ni = 0; ni < 2; ++ni)
          acc[mi][ni] = MFMA16(af[mi], bfr[ni], acc[mi][ni]);
    }
    __builtin_amdgcn_sched_barrier(0);
    __builtin_amdgcn_s_barrier();
  }
#undef GSTAGE

#pragma unroll
  for (int mi = 0; mi < 2; ++mi) {
#pragma unroll
    for (int ni = 0; ni < 2; ++ni) {
      int col = bn * 64 + wn * 32 + ni * 16 + l15;
      float bv = bias[col];
      if (OUTM == 0) {
#pragma unroll
        for (int j = 0; j < 4; ++j) {
          int row = bm * 128 + wm * 32 + mi * 16 + lg * 4 + j;
          reinterpret_cast<float*>(Cout)[(size_t)row * N + col] = acc[mi][ni][j] + bv;
        }
      } else {
        // VF[bh][tg][dh][hi*32+lv][j] = V[tg*16 + hi*8 + j][dh*32 + lv]
        int row0 = bm * 128 + wm * 32 + mi * 16 + lg * 4;
        int b = row0 >> 11, tg = (row0 >> 4) & 127;
        int hi_ = lg >> 1, jb = (lg & 1) << 2;
        int h = col >> 6, hd = col & 63, dh = hd >> 5, lv = hd & 31;
        size_t addr = ((((size_t)(b * 16 + h) * 128 + tg) * 2 + dh) << 9) +
                      ((hi_ * 32 + lv) << 3) + jb;
        ushort4 o;
        o.x = f2b(acc[mi][ni][0] + bv); o.y = f2b(acc[mi][ni][1] + bv);
        o.z = f2b(acc[mi][ni][2] + bv); o.w = f2b(acc[mi][ni][3] + bv);
        *reinterpret_cast<ushort4*>(reinterpret_cast<u16*>(Cout) + addr) = o;
      }
    }
  }
}

// ---------- flash attention: q=128/block, XCD-swizzled grid (r16 best) ----------
__global__ __launch_bounds__(256, 2) void k_attn(const u16* __restrict__ Z,
                                                 const u16* __restrict__ Zg,
                                                 const u32* __restrict__ zghl,
                                                 const u16* __restrict__ VF,
                                                 u16* __restrict__ O) {
  __shared__ __align__(16) char smem[33792];
  float* psqf = reinterpret_cast<float*>(smem + 32768);

  int tid = threadIdx.x, lane = tid & 63, w = tid >> 6;
  int l31 = lane & 31, hi = lane >> 5;
  int hi4 = hi << 2, hi8 = hi << 3;
  int th = w & 1, qh = w >> 1, th32 = th << 5;
  int wg = ((blockIdx.x & 7) << 6) + (blockIdx.x >> 3);
  int bh = wg >> 4, qt = wg & 15;
  int q0 = qt << 7;
  int h = bh & 15, bb = bh >> 4;

  const u16* Zb = Z + ((size_t)bh << 11) * 16;
  const u16* Zgb = Zg + ((size_t)bh << 11) * 16;
  const u32* ghl = zghl + ((size_t)bh << 11);
  const u16* VFb = VF + ((size_t)bh << 17);

  int qx0 = (qh << 6) + l31;
  int qx1 = qx0 + 32;

  bf16x8 zq2_0 = *reinterpret_cast<const bf16x8*>(Zgb + (size_t)(q0 + qx0) * 16 + hi8);
  bf16x8 zq2_1 = *reinterpret_cast<const bf16x8*>(Zgb + (size_t)(q0 + qx1) * 16 + hi8);

  u32 gq0 = ghl[q0 + qx0], gq1 = ghl[q0 + qx1];
  uint4 ab0 = {0x3F803F80u, gq0, 0u, 0u};
  uint4 ab1 = {0x3F803F80u, gq1, 0u, 0u};
  if (hi) { ab0.x = 0u; ab0.y = 0u; ab1.x = 0u; ab1.y = 0u; }
  bf16x8 aug_b0 = *reinterpret_cast<bf16x8*>(&ab0);
  bf16x8 aug_b1 = *reinterpret_cast<bf16x8*>(&ab1);

  uint4 aqu = {0u, 0x3F803F80u, 0u, 0u};
  if (hi) aqu.y = 0u;
  bf16x8 aug_q = *reinterpret_cast<bf16x8*>(&aqu);
  f32x16 qpart0 = MFMA32(aug_q, aug_b0, (f32x16){});
  f32x16 qpart1 = MFMA32(aug_q, aug_b1, (f32x16){});

  const u16* zap = Zb + (size_t)(th32 + l31) * 16 + hi8;
  const u32* xtp = ghl + th32 + l31;
  const u16* vwp = VFb + ((size_t)th << 11) + ((size_t)lane << 3);

  f32x16 oacc00 = {}, oacc01 = {}, oacc10 = {}, oacc11 = {};
  f32x4 ps0 = {}, ps1 = {};

  int swz = (l31 ^ (l31 >> 2)) & 3;
  char* pbase = smem + (w << 12) + l31 * 64;

  bf16x8 zA_c = *reinterpret_cast<const bf16x8*>(zap);
  u32 zhl_c = xtp[0];
  bf16x8 vc0 = *reinterpret_cast<const bf16x8*>(vwp);
  bf16x8 vc1 = *reinterpret_cast<const bf16x8*>(vwp + 512);
  bf16x8 vc2 = *reinterpret_cast<const bf16x8*>(vwp + 1024);
  bf16x8 vc3 = *reinterpret_cast<const bf16x8*>(vwp + 1536);

#pragma unroll 2
  for (int tt = 0; tt < 32; ++tt) {
    const int t0 = tt << 6;
    bf16x8 zA_n = zA_c, vn0 = vc0, vn1 = vc1, vn2 = vc2, vn3 = vc3;
    u32 zhl_n = zhl_c;
    if (tt < 31) {
      const u16* vtb = vwp + ((tt + 1) << 12);
      zA_n = *reinterpret_cast<const bf16x8*>(zap + (size_t)(t0 + 64) * 16);
      zhl_n = xtp[t0 + 64];
      vn0 = *reinterpret_cast<const bf16x8*>(vtb);
      vn1 = *reinterpret_cast<const bf16x8*>(vtb + 512);
      vn2 = *reinterpret_cast<const bf16x8*>(vtb + 1024);
      vn3 = *reinterpret_cast<const bf16x8*>(vtb + 1536);
    }

    uint4 aau = {hi ? 0u : zhl_c, 0u, 0u, 0u};
    bf16x8 aug_a = *reinterpret_cast<bf16x8*>(&aau);

    f32x16 sc0 = MFMA32(aug_a, aug_b0, qpart0);
    sc0 = MFMA32(zA_c, zq2_0, sc0);
    f32x16 sc1 = MFMA32(aug_a, aug_b1, qpart1);
    sc1 = MFMA32(zA_c, zq2_1, sc1);

    char* pb = pbase + ((tt & 1) << 14);
#pragma unroll
    for (int g = 0; g < 4; ++g) {
      int cb = ((g ^ swz) << 4) + (hi << 3);
      {  // q-block 0
        float e0 = fminf(sc0[g * 4 + 0], 0.f), e1 = fminf(sc0[g * 4 + 1], 0.f);
        float e2 = fminf(sc0[g * 4 + 2], 0.f), e3 = fminf(sc0[g * 4 + 3], 0.f);
        float p0 = __builtin_amdgcn_exp2f(e0), p1 = __builtin_amdgcn_exp2f(e1);
        float p2 = __builtin_amdgcn_exp2f(e2), p3 = __builtin_amdgcn_exp2f(e3);
        ps0[0] += p0; ps0[1] += p1; ps0[2] += p2; ps0[3] += p3;
        u32 pk0, pk1;
        asm("v_cvt_pk_bf16_f32 %0, %1, %2" : "=v"(pk0) : "v"(p0), "v"(p1));
        asm("v_cvt_pk_bf16_f32 %0, %1, %2" : "=v"(pk1) : "v"(p2), "v"(p3));
        uint2 pkv = {pk0, pk1};
        *reinterpret_cast<uint2*>(pb + cb) = pkv;
      }
      {  // q-block 1
        float e0 = fminf(sc1[g * 4 + 0], 0.f), e1 = fminf(sc1[g * 4 + 1], 0.f);
        float e2 = fminf(sc1[g * 4 + 2], 0.f), e3 = fminf(sc1[g * 4 + 3], 0.f);
        float p0 = __builtin_amdgcn_exp2f(e0), p1 = __builtin_amdgcn_exp2f(e1);
        float p2 = __builtin_amdgcn_exp2f(e2), p3 = __builtin_amdgcn_exp2f(e3);
        ps1[0] += p0; ps1[1] += p1; ps1[2] += p2; ps1[3] += p3;
        u32 pk0, pk1;
        asm("v_cvt_pk_bf16_f32 %0, %1, %2" : "=v"(pk0) : "v"(p0), "v"(p1));
        asm("v_cvt_pk_bf16_f32 %0, %1, %2" : "=v"(pk1) : "v"(p2), "v"(p3));
        uint2 pkv = {pk0, pk1};
        *reinterpret_cast<uint2*>(pb + 2048 + cb) = pkv;
      }
    }

    int c0b = (((0 * 2 + hi) ^ swz) << 4);
    int c1b = (((1 * 2 + hi) ^ swz) << 4);
    bf16x8 pa00 = *reinterpret_cast<const bf16x8*>(pb + c0b);
    bf16x8 pa01 = *reinterpret_cast<const bf16x8*>(pb + c1b);
    bf16x8 pa10 = *reinterpret_cast<const bf16x8*>(pb + 2048 + c0b);
    bf16x8 pa11 = *reinterpret_cast<const bf16x8*>(pb + 2048 + c1b);

    __builtin_amdgcn_s_setprio(1);
    oacc00 = MFMA32(pa00, vc0, oacc00);
    oacc01 = MFMA32(pa00, vc1, oacc01);
    oacc10 = MFMA32(pa10, vc0, oacc10);
    oacc11 = MFMA32(pa10, vc1, oacc11);
    oacc00 = MFMA32(pa01, vc2, oacc00);
    oacc01 = MFMA32(pa01, vc3, oacc01);
    oacc10 = MFMA32(pa11, vc2, oacc10);
    oacc11 = MFMA32(pa11, vc3, oacc11);
    __builtin_amdgcn_s_setprio(0);

    zA_c = zA_n; zhl_c = zhl_n;
    vc0 = vn0; vc1 = vn1; vc2 = vn2; vc3 = vn3;
  }

  float psum0 = (ps0[0] + ps0[1]) + (ps0[2] + ps0[3]);
  float psum1 = (ps1[0] + ps1[1]) + (ps1[2] + ps1[3]);
  psum0 += __shfl_xor(psum0, 32, 64);
  psum1 += __shfl_xor(psum1, 32, 64);

  __syncthreads();
  if (th == 1) {
    char* dst = smem + ((w >> 1) << 14) + lane * 16;
#pragma unroll
    for (int r = 0; r < 4; ++r) {
      *reinterpret_cast<f32x4*>(dst + (0 + r) * 1024) =
          (f32x4){oacc00[r * 4], oacc00[r * 4 + 1], oacc00[r * 4 + 2], oacc00[r * 4 + 3]};
      *reinterpret_cast<f32x4*>(dst + (4 + r) * 1024) =
          (f32x4){oacc01[r * 4], oacc01[r * 4 + 1], oacc01[r * 4 + 2], oacc01[r * 4 + 3]};
      *reinterpret_cast<f32x4*>(dst + (8 + r) * 1024) =
          (f32x4){oacc10[r * 4], oacc10[r * 4 + 1], oacc10[r * 4 + 2], oacc10[r * 4 + 3]};
      *reinterpret_cast<f32x4*>(dst + (12 + r) * 1024) =
          (f32x4){oacc11[r * 4], oacc11[r * 4 + 1], oacc11[r * 4 + 2], oacc11[r * 4 + 3]};
    }
  }
  if (lane < 32) {
    psqf[(w * 2 + 0) * 32 + l31] = psum0;
    psqf[(w * 2 + 1) * 32 + l31] = psum1;
  }
  __syncthreads();
  if (th == 0) {
    const char* src = smem + ((w >> 1) << 14) + lane * 16;
#pragma unroll
    for (int r = 0; r < 4; ++r) {
      f32x4 v0 = *reinterpret_cast<const f32x4*>(src + (0 + r) * 1024);
      f32x4 v1 = *reinterpret_cast<const f32x4*>(src + (4 + r) * 1024);
      f32x4 v2 = *reinterpret_cast<const f32x4*>(src + (8 + r) * 1024);
      f32x4 v3 = *reinterpret_cast<const f32x4*>(src + (12 + r) * 1024);
#pragma unroll
      for (int j = 0; j < 4; ++j) {
        oacc00[r * 4 + j] += v0[j];
        oacc01[r * 4 + j] += v1[j];
        oacc10[r * 4 + j] += v2[j];
        oacc11[r * 4 + j] += v3[j];
      }
    }
#pragma unroll
    for (int qbk = 0; qbk < 2; ++qbk) {
#pragma unroll
      for (int g = 0; g < 4; ++g) {
        f32x4 a = *reinterpret_cast<const f32x4*>(&psqf[(w * 2 + qbk) * 32 + (g << 3) + hi4]);
        f32x4 b2 = *reinterpret_cast<const f32x4*>(&psqf[((w + 1) * 2 + qbk) * 32 + (g << 3) + hi4]);
#pragma unroll
        for (int j = 0; j < 4; ++j) {
          float inv = __builtin_amdgcn_rcpf(a[j] + b2[j]);
          int qrow = (g << 3) + hi4 + j;
          int srow = q0 + (qh << 6) + (qbk << 5) + qrow;
          u16* orow = O + ((size_t)(bb * 2048 + srow) << 10) + h * 64 + l31;
          float v0 = (qbk ? oacc10[g * 4 + j] : oacc00[g * 4 + j]);
          float v1 = (qbk ? oacc11[g * 4 + j] : oacc01[g * 4 + j]);
          orow[0] = f2b(v0 * inv);
          orow[32] = f2b(v1 * inv);
        }
      }
    }
  }
}

extern "C" void kernel_launch(void* const* d_in, const int* in_sizes, int n_in,
                              void* d_out, int out_size, void* d_ws, size_t ws_size,
                              hipStream_t stream) {
  const float* hs     = (const float*)d_in[0];
  const float* coords = (const float*)d_in[1];
  const float* Wv     = (const float*)d_in[2];
  const float* bv     = (const float*)d_in[3];
  const float* Wc     = (const float*)d_in[4];
  const float* bc     = (const float*)d_in[5];
  const float* Wn     = (const float*)d_in[6];
  const float* bn     = (const float*)d_in[7];
  const float* Wo     = (const float*)d_in[8];
  const float* bo     = (const float*)d_in[9];
  const float* gamma  = (const float*)d_in[10];
  float* out_h = (float*)d_out;
  float* out_c = out_h + 4194304;

  char* ws = (char*)d_ws;
  u16*   HSb  = (u16*)(ws + 0);          // 8 MB (reused as O after gemm1)
  u16*   O    = (u16*)(ws + 0);
  u16*   WvT  = (u16*)(ws + 8388608);    // 2 MB
  u16*   WoT  = (u16*)(ws + 10485760);   // 2 MB
  u16*   Zw   = (u16*)(ws + 12582912);   // 2 MB
  u16*   Zgw  = (u16*)(ws + 14680064);   // 2 MB
  u32*   zghl = (u32*)(ws + 16777216);   // 256 KB
  u16*   VFw  = (u16*)(ws + 17039360);   // 8 MB -> total ~25 MB

  k_prep2<<<4608, 256, 0, stream>>>(hs, HSb, Wv, WvT, Wo, WoT);
  k_z<<<256, 256, 0, stream>>>(coords, Wc, bc, gamma, Zw, Zgw, zghl);
  k_gemm<1><<<512, 512, 0, stream>>>(HSb, WvT, bv, VFw, 4096, 1024, 1024);
  k_attn<<<512, 256, 0, stream>>>(Zw, Zgw, zghl, VFw, O);
  k_gemm<0><<<512, 512, 0, stream>>>(O, WoT, bo, out_h, 4096, 1024, 1024);
  k_coords<<<1024, 256, 0, stream>>>(coords, Wn, bn, out_c);
}